// Round 1
// baseline (264.384 us; speedup 1.0000x reference)
//
#include <hip/hip_runtime.h>

#define HALO 5
#define TW 32
#define TH 32
#define IW 44            // padded LDS stride (42 real cols, +2 pad, keeps float4 alignment)
#define IH 42            // TH + 2*HALO
#define IMG_H 512
#define IMG_W 512
#define N_TOT (16 * 3 * 512 * 512)

// log2(e)/ (2*sigma^2) with sigma=1.5 -> 1/4.5 * 1.4426950408889634
#define NEG_EXP2_SCALE (-0.32059889797532525f)

__global__ __launch_bounds__(256) void ssim_main(const float* __restrict__ pred,
                                                 const float* __restrict__ tgt,
                                                 float* __restrict__ accum) {
    __shared__ __align__(16) float sp[IH * IW];
    __shared__ __align__(16) float st[IH * IW];
    __shared__ __align__(16) float v0[TH * IW];  // vblur(p)
    __shared__ __align__(16) float v1[TH * IW];  // vblur(t)
    __shared__ __align__(16) float v2[TH * IW];  // vblur(p*p)
    __shared__ __align__(16) float v3[TH * IW];  // vblur(t*t)
    __shared__ __align__(16) float v4[TH * IW];  // vblur(p*t)
    __shared__ float red[4];

    // Gaussian weights (win=11, sigma=1.5), normalized — matches jnp f32 to ~1 ulp
    float g[11];
    {
        float s = 0.f;
#pragma unroll
        for (int i = 0; i < 11; ++i) {
            float d = (float)(i - 5);
            g[i] = exp2f(d * d * NEG_EXP2_SCALE);
            s += g[i];
        }
        float inv = 1.0f / s;
#pragma unroll
        for (int i = 0; i < 11; ++i) g[i] *= inv;
    }

    const int tid = threadIdx.x;
    const int tile = blockIdx.x;             // 0..255 (16x16 tiles of 32x32)
    const int plane = blockIdx.y;            // 0..47 (N*C planes)
    const int tx = (tile & 15) * TW;
    const int ty = (tile >> 4) * TH;
    const float* pbase = pred + (size_t)plane * (IMG_H * IMG_W);
    const float* tbase = tgt + (size_t)plane * (IMG_H * IMG_W);

    // ---- Phase 0: stage raw tiles with zero padding ----
    for (int i = tid; i < IH * IW; i += 256) {
        int ly = i / IW;
        int lx = i - ly * IW;
        int gy = ty + ly - HALO;
        int gx = tx + lx - HALO;
        float pv = 0.f, tv = 0.f;
        if (gy >= 0 && gy < IMG_H && gx >= 0 && gx < IMG_W) {
            int gidx = gy * IMG_W + gx;
            pv = pbase[gidx];
            tv = tbase[gidx];
        }
        sp[i] = pv;
        st[i] = tv;
    }
    __syncthreads();

    // ---- Phase 1: vertical 11-tap blur of 5 quantities, 4 columns per thread ----
    // groups: (IW/4)=11 per row x TH=32 rows = 352
    for (int grp = tid; grp < (IW / 4) * TH; grp += 256) {
        int oy = grp / (IW / 4);
        int gx4 = (grp - oy * (IW / 4)) << 2;
        const float* spb = sp + oy * IW + gx4;
        const float* stb = st + oy * IW + gx4;
        float ap[4] = {0, 0, 0, 0}, at[4] = {0, 0, 0, 0};
        float app[4] = {0, 0, 0, 0}, att[4] = {0, 0, 0, 0}, apt[4] = {0, 0, 0, 0};
#pragma unroll
        for (int k = 0; k < 11; ++k) {
            float4 P = *(const float4*)(spb + k * IW);
            float4 T = *(const float4*)(stb + k * IW);
            float p[4] = {P.x, P.y, P.z, P.w};
            float t[4] = {T.x, T.y, T.z, T.w};
            float w = g[k];
#pragma unroll
            for (int j = 0; j < 4; ++j) {
                float wp = w * p[j];
                float wt = w * t[j];
                ap[j] += wp;
                at[j] += wt;
                app[j] = fmaf(wp, p[j], app[j]);
                att[j] = fmaf(wt, t[j], att[j]);
                apt[j] = fmaf(wp, t[j], apt[j]);
            }
        }
        int o = oy * IW + gx4;
        *(float4*)(v0 + o) = make_float4(ap[0], ap[1], ap[2], ap[3]);
        *(float4*)(v1 + o) = make_float4(at[0], at[1], at[2], at[3]);
        *(float4*)(v2 + o) = make_float4(app[0], app[1], app[2], app[3]);
        *(float4*)(v3 + o) = make_float4(att[0], att[1], att[2], att[3]);
        *(float4*)(v4 + o) = make_float4(apt[0], apt[1], apt[2], apt[3]);
    }
    __syncthreads();

    // ---- Phase 2: horizontal 11-tap blur + SSIM map, 4 outputs per thread ----
    float lsum = 0.f;
    {
        int oy = tid >> 3;            // 32 rows
        int ox = (tid & 7) << 2;      // 8 groups of 4 -> 32 cols
        int o = oy * IW + ox;

        float m1[4], m2[4], bpp[4], btt[4], bpt[4];
#define HBLUR(SRC, OUT)                                                        \
        {                                                                      \
            float4 A = *(const float4*)(SRC + o);                              \
            float4 B = *(const float4*)(SRC + o + 4);                          \
            float4 C = *(const float4*)(SRC + o + 8);                          \
            float2 D = *(const float2*)(SRC + o + 12);                         \
            float win[14] = {A.x, A.y, A.z, A.w, B.x, B.y, B.z, B.w,           \
                             C.x, C.y, C.z, C.w, D.x, D.y};                    \
            _Pragma("unroll") for (int j = 0; j < 4; ++j) {                    \
                float acc = 0.f;                                               \
                _Pragma("unroll") for (int k = 0; k < 11; ++k)                 \
                    acc = fmaf(g[k], win[j + k], acc);                         \
                OUT[j] = acc;                                                  \
            }                                                                  \
        }
        HBLUR(v0, m1)
        HBLUR(v1, m2)
        HBLUR(v2, bpp)
        HBLUR(v3, btt)
        HBLUR(v4, bpt)
#undef HBLUR

        const float C1 = 0.0001f;   // 0.01^2
        const float C2 = 0.0009f;   // 0.03^2
#pragma unroll
        for (int j = 0; j < 4; ++j) {
            float mu1 = m1[j], mu2 = m2[j];
            float mu1s = mu1 * mu1;
            float mu2s = mu2 * mu2;
            float mu12 = mu1 * mu2;
            float s1 = bpp[j] - mu1s;
            float s2 = btt[j] - mu2s;
            float s12 = bpt[j] - mu12;
            float num = (2.0f * mu12 + C1) * (2.0f * s12 + C2);
            float den = (mu1s + mu2s + C1) * (s1 + s2 + C2);
            lsum += num / den;
        }
    }

    // ---- Reduction: wave shuffle -> LDS -> one atomic per block ----
#pragma unroll
    for (int off = 32; off > 0; off >>= 1) lsum += __shfl_down(lsum, off, 64);
    if ((tid & 63) == 0) red[tid >> 6] = lsum;
    __syncthreads();
    if (tid == 0) {
        float bs = red[0] + red[1] + red[2] + red[3];
        atomicAdd(accum, bs);
    }
}

__global__ void ssim_final(const float* __restrict__ accum, float* __restrict__ out) {
    out[0] = 1.0f - accum[0] * (1.0f / (float)N_TOT);
}

extern "C" void kernel_launch(void* const* d_in, const int* in_sizes, int n_in,
                              void* d_out, int out_size, void* d_ws, size_t ws_size,
                              hipStream_t stream) {
    const float* pred = (const float*)d_in[0];
    const float* tgt = (const float*)d_in[1];
    float* out = (float*)d_out;
    float* accum = (float*)d_ws;

    hipMemsetAsync(accum, 0, sizeof(float), stream);
    dim3 grid(256, 48);  // 16x16 tiles x (16*3) planes
    ssim_main<<<grid, 256, 0, stream>>>(pred, tgt, accum);
    ssim_final<<<1, 1, 0, stream>>>(accum, out);
}

// Round 2
// 262.399 us; speedup vs baseline: 1.0076x; 1.0076x over previous
//
#include <hip/hip_runtime.h>

#define IMG 512
#define TW 32
#define TH 32
#define NG 12            // float4 col-groups per tile row: 48 cols = 32 out + 8 halo each side (aligned)
#define VS 52            // LDS stride of v-planes (48 valid cols + 4 pad -> breaks bank pattern)
#define N_TOT (16 * 3 * 512 * 512)

// Gaussian(win=11, sigma=1.5), normalized; precomputed to ~7 digits (final-scalar
// error ~1e-6 vs threshold 1.98e-2). Live as SGPR constants, not VGPRs.
__device__ __constant__ const float Gw[11] = {
    0.00102838f, 0.00759876f, 0.03600077f, 0.10936086f, 0.21300537f,
    0.26601173f, 0.21300537f, 0.10936086f, 0.03600077f, 0.00759876f,
    0.00102838f};

__global__ __launch_bounds__(256) void ssim_main(const float* __restrict__ pred,
                                                 const float* __restrict__ tgt,
                                                 float* __restrict__ accum) {
    // 4 vertically-blurred planes: p, t, p^2+t^2, p*t  (32 rows x 48 cols, stride 52)
    __shared__ __align__(16) float v[4][TH * VS];
    __shared__ float red[4];

    const int tid = threadIdx.x;
    const int tile = blockIdx.x;             // 16x16 tiles of 32x32
    const int plane = blockIdx.y;            // 48 planes
    const int tx = (tile & 15) * TW;
    const int ty = (tile >> 4) * TH;
    const float* pbase = pred + (size_t)plane * (IMG * IMG);
    const float* tbase = tgt + (size_t)plane * (IMG * IMG);

    // ---- Phase 1: vertical 11-tap blur straight from global, row-pair per task ----
    // 192 tasks = 12 col-groups x 16 row-pairs. Each task: 12 aligned float4 row-loads
    // per input array -> 2 output rows x 4 cols x 4 quantities.
    if (tid < NG * 16) {
        const int g4 = tid % NG;             // col group
        const int rp = tid / NG;             // row pair
        const int r0 = rp * 2;               // local output row
        const int col = tx - 8 + (g4 << 2);  // global col of float4 (16B-aligned)
        const bool xin = (unsigned)col < (unsigned)IMG;  // 512%4==0 -> all-in or all-out
        const int ybase = ty + r0 - 5;

        float a0[4][4], a1[4][4];
#pragma unroll
        for (int q = 0; q < 4; ++q)
#pragma unroll
            for (int j = 0; j < 4; ++j) { a0[q][j] = 0.f; a1[q][j] = 0.f; }

#pragma unroll
        for (int k = 0; k < 12; ++k) {
            const int y = ybase + k;
            float4 P = make_float4(0.f, 0.f, 0.f, 0.f);
            float4 T = make_float4(0.f, 0.f, 0.f, 0.f);
            if (xin && (unsigned)y < (unsigned)IMG) {
                const int gidx = y * IMG + col;
                P = *(const float4*)(pbase + gidx);
                T = *(const float4*)(tbase + gidx);
            }
            const float p[4] = {P.x, P.y, P.z, P.w};
            const float t[4] = {T.x, T.y, T.z, T.w};
#pragma unroll
            for (int j = 0; j < 4; ++j) {
                const float ss = fmaf(p[j], p[j], t[j] * t[j]);
                const float pt = p[j] * t[j];
                if (k < 11) {                 // tap k for row r0
                    const float w = Gw[k];
                    a0[0][j] = fmaf(w, p[j], a0[0][j]);
                    a0[1][j] = fmaf(w, t[j], a0[1][j]);
                    a0[2][j] = fmaf(w, ss, a0[2][j]);
                    a0[3][j] = fmaf(w, pt, a0[3][j]);
                }
                if (k > 0) {                  // tap k-1 for row r0+1
                    const float w = Gw[k - 1];
                    a1[0][j] = fmaf(w, p[j], a1[0][j]);
                    a1[1][j] = fmaf(w, t[j], a1[1][j]);
                    a1[2][j] = fmaf(w, ss, a1[2][j]);
                    a1[3][j] = fmaf(w, pt, a1[3][j]);
                }
            }
        }
        const int o = r0 * VS + (g4 << 2);
#pragma unroll
        for (int q = 0; q < 4; ++q) {
            *(float4*)(&v[q][o]) = make_float4(a0[q][0], a0[q][1], a0[q][2], a0[q][3]);
            *(float4*)(&v[q][o + VS]) = make_float4(a1[q][0], a1[q][1], a1[q][2], a1[q][3]);
        }
    }
    __syncthreads();

    // ---- Phase 2: horizontal 11-tap blur + SSIM map, 4 outputs per thread ----
    float lsum = 0.f;
    {
        const int oy = tid >> 3;             // 32 rows
        const int ox = (tid & 7) << 2;       // 8 groups of 4 cols
        const int o = oy * VS + ox;

        float out[4][4];
#pragma unroll
        for (int q = 0; q < 4; ++q) {
            float win[20];
#pragma unroll
            for (int b = 0; b < 5; ++b) {
                const float4 W = *(const float4*)(&v[q][o + (b << 2)]);
                win[4 * b + 0] = W.x;
                win[4 * b + 1] = W.y;
                win[4 * b + 2] = W.z;
                win[4 * b + 3] = W.w;
            }
            // output global col tx+ox+j reads local cols (ox+j+3) .. (ox+j+13)
#pragma unroll
            for (int j = 0; j < 4; ++j) {
                float acc = 0.f;
#pragma unroll
                for (int k = 0; k < 11; ++k)
                    acc = fmaf(Gw[k], win[3 + j + k], acc);
                out[q][j] = acc;
            }
        }

        const float C1 = 0.0001f;            // 0.01^2
        const float C2 = 0.0009f;            // 0.03^2
#pragma unroll
        for (int j = 0; j < 4; ++j) {
            const float mu1 = out[0][j], mu2 = out[1][j];
            const float mu1s = mu1 * mu1;
            const float mu2s = mu2 * mu2;
            const float mu12 = mu1 * mu2;
            const float A = mu1s + mu2s;
            const float s12 = out[3][j] - mu12;     // sigma12
            const float sden = out[2][j] - A;       // sigma1^2 + sigma2^2
            const float num = fmaf(2.f, mu12, C1) * fmaf(2.f, s12, C2);
            const float den = (A + C1) * (sden + C2);
            lsum += num / den;
        }
    }

    // ---- Reduction: wave shuffle -> LDS -> one atomic per block ----
#pragma unroll
    for (int off = 32; off > 0; off >>= 1) lsum += __shfl_down(lsum, off, 64);
    if ((tid & 63) == 0) red[tid >> 6] = lsum;
    __syncthreads();
    if (tid == 0) {
        const float bs = red[0] + red[1] + red[2] + red[3];
        atomicAdd(accum, bs);
    }
}

__global__ void ssim_final(const float* __restrict__ accum, float* __restrict__ out) {
    out[0] = 1.0f - accum[0] * (1.0f / (float)N_TOT);
}

extern "C" void kernel_launch(void* const* d_in, const int* in_sizes, int n_in,
                              void* d_out, int out_size, void* d_ws, size_t ws_size,
                              hipStream_t stream) {
    const float* pred = (const float*)d_in[0];
    const float* tgt = (const float*)d_in[1];
    float* out = (float*)d_out;
    float* accum = (float*)d_ws;

    hipMemsetAsync(accum, 0, sizeof(float), stream);
    dim3 grid(256, 48);  // 16x16 tiles x (16*3) planes
    ssim_main<<<grid, 256, 0, stream>>>(pred, tgt, accum);
    ssim_final<<<1, 1, 0, stream>>>(accum, out);
}

// Round 3
// 177.097 us; speedup vs baseline: 1.4929x; 1.4817x over previous
//
#include <hip/hip_runtime.h>

#define IMG 512
#define TW 32
#define TH 32
#define NG 12            // float4 col-groups per tile row: 48 cols = 32 out + 8 halo each side (aligned)
#define VS 52            // LDS stride of v-planes (48 valid cols + 4 pad -> breaks bank pattern)
#define N_TOT (16 * 3 * 512 * 512)
#define NBLK (256 * 48)  // total blocks of ssim_main
#define NSLOT 1024       // fallback atomic slots

// Gaussian(win=11, sigma=1.5), normalized.
__device__ __constant__ const float Gw[11] = {
    0.00102838f, 0.00759876f, 0.03600077f, 0.10936086f, 0.21300537f,
    0.26601173f, 0.21300537f, 0.10936086f, 0.03600077f, 0.00759876f,
    0.00102838f};

__global__ __launch_bounds__(256) void ssim_main(const float* __restrict__ pred,
                                                 const float* __restrict__ tgt,
                                                 float* __restrict__ ws,
                                                 int parts_mode) {
    // 4 vertically-blurred planes: p, t, p^2+t^2, p*t  (32 rows x 48 cols, stride 52)
    __shared__ __align__(16) float v[4][TH * VS];
    __shared__ float red[4];

    const int tid = threadIdx.x;
    const int tile = blockIdx.x;             // 16x16 tiles of 32x32
    const int plane = blockIdx.y;            // 48 planes
    const int tx = (tile & 15) * TW;
    const int ty = (tile >> 4) * TH;
    const float* pbase = pred + (size_t)plane * (IMG * IMG);
    const float* tbase = tgt + (size_t)plane * (IMG * IMG);

    // ---- Phase 1: vertical 11-tap blur straight from global, row-pair per task ----
    if (tid < NG * 16) {
        const int g4 = tid % NG;             // col group
        const int rp = tid / NG;             // row pair
        const int r0 = rp * 2;               // local output row
        const int col = tx - 8 + (g4 << 2);  // global col of float4 (16B-aligned)
        const bool xin = (unsigned)col < (unsigned)IMG;  // 512%4==0 -> all-in or all-out
        const int ybase = ty + r0 - 5;

        float a0[4][4], a1[4][4];
#pragma unroll
        for (int q = 0; q < 4; ++q)
#pragma unroll
            for (int j = 0; j < 4; ++j) { a0[q][j] = 0.f; a1[q][j] = 0.f; }

#pragma unroll
        for (int k = 0; k < 12; ++k) {
            const int y = ybase + k;
            float4 P = make_float4(0.f, 0.f, 0.f, 0.f);
            float4 T = make_float4(0.f, 0.f, 0.f, 0.f);
            if (xin && (unsigned)y < (unsigned)IMG) {
                const int gidx = y * IMG + col;
                P = *(const float4*)(pbase + gidx);
                T = *(const float4*)(tbase + gidx);
            }
            const float p[4] = {P.x, P.y, P.z, P.w};
            const float t[4] = {T.x, T.y, T.z, T.w};
#pragma unroll
            for (int j = 0; j < 4; ++j) {
                const float ss = fmaf(p[j], p[j], t[j] * t[j]);
                const float pt = p[j] * t[j];
                if (k < 11) {                 // tap k for row r0
                    const float w = Gw[k];
                    a0[0][j] = fmaf(w, p[j], a0[0][j]);
                    a0[1][j] = fmaf(w, t[j], a0[1][j]);
                    a0[2][j] = fmaf(w, ss, a0[2][j]);
                    a0[3][j] = fmaf(w, pt, a0[3][j]);
                }
                if (k > 0) {                  // tap k-1 for row r0+1
                    const float w = Gw[k - 1];
                    a1[0][j] = fmaf(w, p[j], a1[0][j]);
                    a1[1][j] = fmaf(w, t[j], a1[1][j]);
                    a1[2][j] = fmaf(w, ss, a1[2][j]);
                    a1[3][j] = fmaf(w, pt, a1[3][j]);
                }
            }
        }
        const int o = r0 * VS + (g4 << 2);
#pragma unroll
        for (int q = 0; q < 4; ++q) {
            *(float4*)(&v[q][o]) = make_float4(a0[q][0], a0[q][1], a0[q][2], a0[q][3]);
            *(float4*)(&v[q][o + VS]) = make_float4(a1[q][0], a1[q][1], a1[q][2], a1[q][3]);
        }
    }
    __syncthreads();

    // ---- Phase 2: horizontal 11-tap blur + SSIM map, 4 outputs per thread ----
    float lsum = 0.f;
    {
        const int oy = tid >> 3;             // 32 rows
        const int ox = (tid & 7) << 2;       // 8 groups of 4 cols
        const int o = oy * VS + ox;

        float out[4][4];
#pragma unroll
        for (int q = 0; q < 4; ++q) {
            float win[20];
#pragma unroll
            for (int b = 0; b < 5; ++b) {
                const float4 W = *(const float4*)(&v[q][o + (b << 2)]);
                win[4 * b + 0] = W.x;
                win[4 * b + 1] = W.y;
                win[4 * b + 2] = W.z;
                win[4 * b + 3] = W.w;
            }
#pragma unroll
            for (int j = 0; j < 4; ++j) {
                float acc = 0.f;
#pragma unroll
                for (int k = 0; k < 11; ++k)
                    acc = fmaf(Gw[k], win[3 + j + k], acc);
                out[q][j] = acc;
            }
        }

        const float C1 = 0.0001f;            // 0.01^2
        const float C2 = 0.0009f;            // 0.03^2
#pragma unroll
        for (int j = 0; j < 4; ++j) {
            const float mu1 = out[0][j], mu2 = out[1][j];
            const float mu1s = mu1 * mu1;
            const float mu2s = mu2 * mu2;
            const float mu12 = mu1 * mu2;
            const float A = mu1s + mu2s;
            const float s12 = out[3][j] - mu12;     // sigma12
            const float sden = out[2][j] - A;       // sigma1^2 + sigma2^2
            const float num = fmaf(2.f, mu12, C1) * fmaf(2.f, s12, C2);
            const float den = (A + C1) * (sden + C2);
            lsum += num / den;
        }
    }

    // ---- Reduction: wave shuffle -> LDS -> ONE PLAIN STORE per block (no atomic) ----
#pragma unroll
    for (int off = 32; off > 0; off >>= 1) lsum += __shfl_down(lsum, off, 64);
    if ((tid & 63) == 0) red[tid >> 6] = lsum;
    __syncthreads();
    if (tid == 0) {
        const float bs = red[0] + red[1] + red[2] + red[3];
        const int bid = blockIdx.y * gridDim.x + blockIdx.x;
        if (parts_mode) {
            ws[bid] = bs;                    // contention-free
        } else {
            atomicAdd(&ws[bid & (NSLOT - 1)], bs);  // fallback: 12-deep contention
        }
    }
}

// Sum `count` partials from ws, write 1 - sum/N.
__global__ __launch_bounds__(256) void ssim_final(const float* __restrict__ ws,
                                                  float* __restrict__ out, int count) {
    __shared__ float red[4];
    const int tid = threadIdx.x;
    float s = 0.f;
    for (int i = tid; i < count; i += 256) s += ws[i];
#pragma unroll
    for (int off = 32; off > 0; off >>= 1) s += __shfl_down(s, off, 64);
    if ((tid & 63) == 0) red[tid >> 6] = s;
    __syncthreads();
    if (tid == 0) {
        const float tot = red[0] + red[1] + red[2] + red[3];
        out[0] = 1.0f - tot * (1.0f / (float)N_TOT);
    }
}

extern "C" void kernel_launch(void* const* d_in, const int* in_sizes, int n_in,
                              void* d_out, int out_size, void* d_ws, size_t ws_size,
                              hipStream_t stream) {
    const float* pred = (const float*)d_in[0];
    const float* tgt = (const float*)d_in[1];
    float* out = (float*)d_out;
    float* ws = (float*)d_ws;

    const int parts_mode = (ws_size >= (size_t)NBLK * sizeof(float)) ? 1 : 0;
    if (!parts_mode) {
        hipMemsetAsync(ws, 0, NSLOT * sizeof(float), stream);
    }
    dim3 grid(256, 48);  // 16x16 tiles x (16*3) planes
    ssim_main<<<grid, 256, 0, stream>>>(pred, tgt, ws, parts_mode);
    ssim_final<<<1, 256, 0, stream>>>(ws, out, parts_mode ? NBLK : NSLOT);
}